// Round 5
// baseline (2151.014 us; speedup 1.0000x reference)
//
#include <hip/hip_runtime.h>
#include <hip/hip_bf16.h>
#include <math.h>

typedef __hip_bfloat16 bf16;

#define BATCH 8
#define HH 112
#define WW 112
#define CDIM 192
#define HEADS 6
#define HD 32
#define QKVW 576
#define MLPW 768
#define WS 7
#define WS2 49
#define NWH 16
#define NWW 16
#define NWIN 256
#define NTOK (BATCH*HH*WW)   // 100352
#define NEGV (-1e9f)
#define TTILE 16

__device__ __forceinline__ float toF(float v) { return v; }
__device__ __forceinline__ float toF(bf16 v) { return __bfloat162float(v); }
__device__ __forceinline__ bf16  f2b(float v) { return __float2bfloat16(v); }

// Per-array dtype probe (first 16 words). bf16 data: both halves of every
// nonzero word have bf16 exponent in [0x60,0x9F]. fp32 data: low halves are
// random mantissa bits (P(all in-band) ~ 2e-10). All-zero probe -> bf16 read,
// which is safe for either dtype (fp32 0.0 halves are 0x0000 == bf16 zero).
__device__ __forceinline__ bool probe_is_bf16(const void* p) {
    const unsigned int* w = (const unsigned int*)p;
    int nz = 0, band = 0;
    #pragma unroll
    for (int i = 0; i < 16; i++) {
        unsigned int v = w[i];
        if (v == 0u) continue;
        nz++;
        unsigned int lo = v & 0xFFFFu, hi = v >> 16;
        unsigned int elo = (lo >> 7) & 0xFFu, ehi = (hi >> 7) & 0xFFu;
        bool okl = (lo != 0u) && (elo >= 0x60u) && (elo <= 0x9Fu);
        bool okh = (hi != 0u) && (ehi >= 0x60u) && (ehi <= 0x9Fu);
        if (okl && okh) band++;
    }
    return (nz == 0) || (band == nz);
}

__device__ __forceinline__ float read_any(const void* p, size_t i, bool isb) {
    return isb ? toF(((const bf16*)p)[i]) : ((const float*)p)[i];
}

__device__ __forceinline__ float wave_sum(float v) {
    #pragma unroll
    for (int o = 1; o < 64; o <<= 1) v += __shfl_xor(v, o, 64);
    return v;
}

// ---------------- Canonicalize one param array to fp32 ----------------
__global__ void canon_kernel(const void* __restrict__ src, float* __restrict__ dst, int n) {
    bool isb = probe_is_bf16(src);
    int i = blockIdx.x * 256 + threadIdx.x;
    if (i < n) dst[i] = read_any(src, i, isb);
}

// ---------------- LN1: raw x (probed) -> bf16, token-major ----------------
__global__ void ln1_kernel(const void* __restrict__ xraw, const float* __restrict__ g,
                           const float* __restrict__ bta, bf16* __restrict__ out) {
    bool xb = probe_is_bf16(xraw);
    int wave = threadIdx.x >> 6, lane = threadIdx.x & 63;
    int t = blockIdx.x * 4 + wave;
    size_t base = (size_t)t * CDIM;
    float v[3];
    #pragma unroll
    for (int i = 0; i < 3; i++) v[i] = read_any(xraw, base + lane + 64 * i, xb);
    float s  = v[0] + v[1] + v[2];
    float s2 = v[0]*v[0] + v[1]*v[1] + v[2]*v[2];
    s = wave_sum(s); s2 = wave_sum(s2);
    float mu = s * (1.0f / CDIM);
    float var = s2 * (1.0f / CDIM) - mu * mu;
    float rs = rsqrtf(var + 1e-5f);
    #pragma unroll
    for (int i = 0; i < 3; i++) {
        int c = lane + 64 * i;
        out[base + c] = f2b((v[i] - mu) * rs * g[c] + bta[c]);
    }
}

// ---------------- LN2: bf16 -> bf16, token-major ----------------
__global__ void ln2_kernel(const bf16* __restrict__ x, const float* __restrict__ g,
                           const float* __restrict__ bta, bf16* __restrict__ out) {
    int wave = threadIdx.x >> 6, lane = threadIdx.x & 63;
    int t = blockIdx.x * 4 + wave;
    size_t base = (size_t)t * CDIM;
    float v[3];
    #pragma unroll
    for (int i = 0; i < 3; i++) v[i] = toF(x[base + lane + 64 * i]);
    float s  = v[0] + v[1] + v[2];
    float s2 = v[0]*v[0] + v[1]*v[1] + v[2]*v[2];
    s = wave_sum(s); s2 = wave_sum(s2);
    float mu = s * (1.0f / CDIM);
    float var = s2 * (1.0f / CDIM) - mu * mu;
    float rs = rsqrtf(var + 1e-5f);
    #pragma unroll
    for (int i = 0; i < 3; i++) {
        int c = lane + 64 * i;
        out[base + c] = f2b((v[i] - mu) * rs * g[c] + bta[c]);
    }
}

// ---------------- QKV: pure token-major GEMM 192->576 ----------------
__global__ void qkv_kernel(const bf16* __restrict__ ln1, const float* __restrict__ wqkv,
                           bf16* __restrict__ qkv) {
    __shared__ float xs[CDIM][TTILE];
    int t0 = blockIdx.x * TTILE;
    int tid = threadIdx.x;
    for (int idx = tid; idx < CDIM * TTILE; idx += 256) {
        int tl = idx / CDIM, ch = idx % CDIM;
        xs[ch][tl] = toF(ln1[(size_t)(t0 + tl) * CDIM + ch]);
    }
    __syncthreads();
    for (int c = tid; c < QKVW; c += 256) {
        float acc[TTILE];
        #pragma unroll
        for (int t = 0; t < TTILE; t++) acc[t] = 0.f;
        for (int k = 0; k < CDIM; k++) {
            float w = wqkv[(size_t)k * QKVW + c];
            #pragma unroll
            for (int t = 0; t < TTILE; t++) acc[t] += xs[k][t] * w;
        }
        #pragma unroll
        for (int t = 0; t < TTILE; t++) qkv[(size_t)(t0 + t) * QKVW + c] = f2b(acc[t]);
    }
}

// ---------------- Window attention: gather/scatter token-major ----------------
// One 64-thread block per (batch, window, head). The cyclic shift exists ONLY
// here as the gather pattern: window-frame (pi,pj) <-> token ((w*7+p+3)%112).
// Output scatters back to the same tokens (+3/-3 rolls cancel pointwise).
__global__ void attn_kernel(const bf16* __restrict__ qkv, const float* __restrict__ pos_emb,
                            bf16* __restrict__ y) {
    __shared__ int   toks[WS2];
    __shared__ float qs[WS2 * 33];
    __shared__ float ks[WS2 * 33];
    __shared__ float vs[WS2 * 33];
    __shared__ float sc[WS2 * 50];
    int bx = blockIdx.x;
    int h = bx % HEADS;
    int rest = bx / HEADS;
    int win = rest % NWIN;
    int b   = rest / NWIN;
    int wi = win / NWW, wj = win % NWW;
    int tid = threadIdx.x;

    if (tid < WS2) {
        int pi = tid / WS, pj = tid % WS;
        int ui = (wi * WS + pi + 3) % HH;
        int uj = (wj * WS + pj + 3) % WW;
        toks[tid] = (b * HH + ui) * WW + uj;
    }
    __syncthreads();

    for (int idx = tid; idx < WS2 * HD; idx += 64) {
        int p = idx >> 5, d = idx & 31;
        size_t base = (size_t)toks[p] * QKVW + h * HD + d;
        qs[p * 33 + d] = toF(qkv[base]);
        ks[p * 33 + d] = toF(qkv[base + CDIM]);
        vs[p * 33 + d] = toF(qkv[base + 2 * CDIM]);
    }
    __syncthreads();

    bool m_ul = (wi == NWH - 1);
    bool m_lr = (wj == NWW - 1);
    for (int e = tid; e < WS2 * WS2; e += 64) {
        int i = e / WS2, j = e % WS2;
        float acc = 0.f;
        #pragma unroll
        for (int d = 0; d < HD; d++) acc += qs[i * 33 + d] * ks[j * 33 + d];
        acc *= 0.17677669529663689f;  // 1/sqrt(32)
        int pi = i / WS, pj = i % WS, kpi = j / WS, kpj = j % WS;
        acc += pos_emb[(pi - kpi + 6) * 13 + (pj - kpj + 6)];
        if (m_ul && ((pi >= 4) != (kpi >= 4))) acc += NEGV;
        if (m_lr && ((pj >= 4) != (kpj >= 4))) acc += NEGV;
        sc[i * 50 + j] = acc;
    }
    __syncthreads();

    if (tid < WS2) {
        float mx = -INFINITY;
        for (int j = 0; j < WS2; j++) mx = fmaxf(mx, sc[tid * 50 + j]);
        float sum = 0.f;
        for (int j = 0; j < WS2; j++) {
            float ev = expf(sc[tid * 50 + j] - mx);
            sc[tid * 50 + j] = ev;
            sum += ev;
        }
        float inv = 1.0f / sum;
        for (int j = 0; j < WS2; j++) sc[tid * 50 + j] *= inv;
    }
    __syncthreads();

    for (int o = tid; o < WS2 * HD; o += 64) {
        int i = o >> 5, d = o & 31;
        float acc = 0.f;
        for (int j = 0; j < WS2; j++) acc += sc[i * 50 + j] * vs[j * 33 + d];
        y[(size_t)toks[i] * CDIM + h * HD + d] = f2b(acc);
    }
}

// ---------------- Projection + residual: pure token-major ----------------
__global__ void proj_kernel(const bf16* __restrict__ y, const float* __restrict__ wout,
                            const float* __restrict__ bout, const void* __restrict__ xraw,
                            bf16* __restrict__ x1) {
    bool xb = probe_is_bf16(xraw);
    __shared__ float ys[CDIM][TTILE];
    int t0 = blockIdx.x * TTILE;
    int tid = threadIdx.x;
    for (int idx = tid; idx < CDIM * TTILE; idx += 256) {
        int tl = idx / CDIM, ch = idx % CDIM;
        ys[ch][tl] = toF(y[(size_t)(t0 + tl) * CDIM + ch]);
    }
    __syncthreads();
    int c = tid;
    if (c < CDIM) {
        float acc[TTILE];
        #pragma unroll
        for (int t = 0; t < TTILE; t++) acc[t] = 0.f;
        for (int k = 0; k < CDIM; k++) {
            float w = wout[(size_t)k * CDIM + c];
            #pragma unroll
            for (int t = 0; t < TTILE; t++) acc[t] += ys[k][t] * w;
        }
        float bo = bout[c];
        #pragma unroll
        for (int t = 0; t < TTILE; t++) {
            size_t o = (size_t)(t0 + t) * CDIM + c;
            x1[o] = f2b(read_any(xraw, o, xb) + bo + acc[t]);
        }
    }
}

// ---------------- MLP1 + exact GELU ----------------
__global__ void mlp1_kernel(const bf16* __restrict__ ln2, const float* __restrict__ w1,
                            const float* __restrict__ b1, bf16* __restrict__ hid) {
    __shared__ float xs[CDIM][TTILE];
    int t0 = blockIdx.x * TTILE;
    int tid = threadIdx.x;
    for (int idx = tid; idx < CDIM * TTILE; idx += 256) {
        int tl = idx / CDIM, ch = idx % CDIM;
        xs[ch][tl] = toF(ln2[(size_t)(t0 + tl) * CDIM + ch]);
    }
    __syncthreads();
    for (int m = tid; m < MLPW; m += 256) {
        float acc[TTILE];
        #pragma unroll
        for (int t = 0; t < TTILE; t++) acc[t] = 0.f;
        for (int k = 0; k < CDIM; k++) {
            float w = w1[(size_t)k * MLPW + m];
            #pragma unroll
            for (int t = 0; t < TTILE; t++) acc[t] += xs[k][t] * w;
        }
        float bb = b1[m];
        #pragma unroll
        for (int t = 0; t < TTILE; t++) {
            float a = acc[t] + bb;
            float gl = 0.5f * a * (1.0f + erff(a * 0.70710678118654752f));
            hid[(size_t)(t0 + t) * MLPW + m] = f2b(gl);
        }
    }
}

// ---------------- MLP2 + residual -> out (FP32 output!) ----------------
__global__ void mlp2_kernel(const bf16* __restrict__ hid, const float* __restrict__ w2,
                            const float* __restrict__ b2v, const bf16* __restrict__ x1,
                            float* __restrict__ out) {
    __shared__ float hs[MLPW][TTILE];   // 48 KiB
    int t0 = blockIdx.x * TTILE;
    int tid = threadIdx.x;
    for (int idx = tid; idx < MLPW * TTILE; idx += 256) {
        int tl = idx / MLPW, ch = idx % MLPW;
        hs[ch][tl] = toF(hid[(size_t)(t0 + tl) * MLPW + ch]);
    }
    __syncthreads();
    int c = tid;
    if (c < CDIM) {
        float acc[TTILE];
        #pragma unroll
        for (int t = 0; t < TTILE; t++) acc[t] = 0.f;
        for (int m = 0; m < MLPW; m++) {
            float w = w2[(size_t)m * CDIM + c];
            #pragma unroll
            for (int t = 0; t < TTILE; t++) acc[t] += hs[m][t] * w;
        }
        float bb = b2v[c];
        #pragma unroll
        for (int t = 0; t < TTILE; t++) {
            size_t o = (size_t)(t0 + t) * CDIM + c;
            out[o] = toF(x1[o]) + bb + acc[t];   // fp32 store — reference output dtype
        }
    }
}

extern "C" void kernel_launch(void* const* d_in, const int* in_sizes, int n_in,
                              void* d_out, int out_size, void* d_ws, size_t ws_size,
                              hipStream_t stream) {
    float* out = (float*)d_out;   // reference returns float32 -> d_out is float*

    // Workspace (233.0 MB total; harness provides >= 269 MB, proven in round 1):
    //   bufA bf16 [NTOK,192]  ln1 / ln2            38,535,168 B
    //   bufQ bf16 [NTOK,576]  qkv, token-major    115,605,504 B
    //   bufY bf16 [NTOK,192]  attn out y           38,535,168 B
    //   bufX bf16 [NTOK,192]  x1                   38,535,168 B
    //   cW   fp32 canonical params                  1,777,920 B
    // MLP hidden [NTOK,768] bf16 overlays bufQ+bufY exactly (both dead by then).
    size_t szA = (size_t)NTOK * CDIM * sizeof(bf16);
    size_t szQ = (size_t)NTOK * QKVW * sizeof(bf16);
    size_t szY = (size_t)NTOK * CDIM * sizeof(bf16);
    size_t szX = (size_t)NTOK * CDIM * sizeof(bf16);
    size_t cwFloats = 444480;
    if (ws_size < szA + szQ + szY + szX + cwFloats * 4) return;
    bf16*  bufA = (bf16*)d_ws;
    bf16*  bufQ = (bf16*)((char*)d_ws + szA);
    bf16*  bufY = (bf16*)((char*)d_ws + szA + szQ);
    bf16*  bufX = (bf16*)((char*)d_ws + szA + szQ + szY);
    float* cW   = (float*)((char*)d_ws + szA + szQ + szY + szX);
    bf16*  hid  = bufQ;   // [NTOK,768] == szQ + szY bytes exactly

    float* cWqkv = cW + 0;
    float* cWout = cW + 110592;
    float* cBout = cW + 147456;
    float* cPe   = cW + 147648;
    float* cL1g  = cW + 147840;
    float* cL1b  = cW + 148032;
    float* cL2g  = cW + 148224;
    float* cL2b  = cW + 148416;
    float* cW1   = cW + 148608;
    float* cB1   = cW + 296064;
    float* cW2   = cW + 296832;
    float* cB2   = cW + 444288;

    dim3 b256(256), b64(64);
    #define CANON(src, dst, n) canon_kernel<<<((n)+255)/256, b256, 0, stream>>>((src), (dst), (n))
    CANON(d_in[1],  cWqkv, CDIM * QKVW);
    CANON(d_in[2],  cWout, CDIM * CDIM);
    CANON(d_in[3],  cBout, 192);
    CANON(d_in[4],  cPe,   169);
    CANON(d_in[5],  cL1g,  192);
    CANON(d_in[6],  cL1b,  192);
    CANON(d_in[7],  cL2g,  192);
    CANON(d_in[8],  cL2b,  192);
    CANON(d_in[9],  cW1,   CDIM * MLPW);
    CANON(d_in[10], cB1,   768);
    CANON(d_in[11], cW2,   MLPW * CDIM);
    CANON(d_in[12], cB2,   192);
    #undef CANON

    int gLN = NTOK / 4;             // 25088
    int gT  = NTOK / TTILE;         // 6272
    int gAT = BATCH * NWIN * HEADS; // 12288

    ln1_kernel<<<gLN, b256, 0, stream>>>(d_in[0], cL1g, cL1b, bufA);
    qkv_kernel<<<gT, b256, 0, stream>>>(bufA, cWqkv, bufQ);
    attn_kernel<<<gAT, b64, 0, stream>>>(bufQ, cPe, bufY);
    proj_kernel<<<gT, b256, 0, stream>>>(bufY, cWout, cBout, d_in[0], bufX);
    ln2_kernel<<<gLN, b256, 0, stream>>>(bufX, cL2g, cL2b, bufA);
    mlp1_kernel<<<gT, b256, 0, stream>>>(bufA, cW1, cB1, hid);
    mlp2_kernel<<<gT, b256, 0, stream>>>(hid, cW2, cB2, bufX, out);
}

// Round 6
// 971.364 us; speedup vs baseline: 2.2144x; 2.2144x over previous
//
#include <hip/hip_runtime.h>
#include <hip/hip_bf16.h>
#include <math.h>

typedef __hip_bfloat16 bf16;
typedef unsigned short ushort_t;
typedef __bf16 bf16x8 __attribute__((ext_vector_type(8)));
typedef float  f32x4  __attribute__((ext_vector_type(4)));

#define BATCH 8
#define HH 112
#define WW 112
#define CDIM 192
#define HEADS 6
#define HD 32
#define QKVW 576
#define MLPW 768
#define WS 7
#define WS2 49
#define NWH 16
#define NWW 16
#define NWIN 256
#define NTOK (BATCH*HH*WW)   // 100352
#define NEGV (-1e9f)

__device__ __forceinline__ float toF(float v) { return v; }
__device__ __forceinline__ float toF(bf16 v) { return __bfloat162float(v); }
__device__ __forceinline__ bf16  f2b(float v) { return __float2bfloat16(v); }
__device__ __forceinline__ ushort_t f2u(float v) { bf16 b = __float2bfloat16(v); return *(ushort_t*)&b; }

// Per-array dtype probe (first 16 words) -- see round-3 notes. Deterministic.
__device__ __forceinline__ bool probe_is_bf16(const void* p) {
    const unsigned int* w = (const unsigned int*)p;
    int nz = 0, band = 0;
    #pragma unroll
    for (int i = 0; i < 16; i++) {
        unsigned int v = w[i];
        if (v == 0u) continue;
        nz++;
        unsigned int lo = v & 0xFFFFu, hi = v >> 16;
        unsigned int elo = (lo >> 7) & 0xFFu, ehi = (hi >> 7) & 0xFFu;
        bool okl = (lo != 0u) && (elo >= 0x60u) && (elo <= 0x9Fu);
        bool okh = (hi != 0u) && (ehi >= 0x60u) && (ehi <= 0x9Fu);
        if (okl && okh) band++;
    }
    return (nz == 0) || (band == nz);
}

__device__ __forceinline__ float read_any(const void* p, size_t i, bool isb) {
    return isb ? toF(((const bf16*)p)[i]) : ((const float*)p)[i];
}

__device__ __forceinline__ float wave_sum(float v) {
    #pragma unroll
    for (int o = 1; o < 64; o <<= 1) v += __shfl_xor(v, o, 64);
    return v;
}

// ---------------- Canonicalize params: fp32 (small vectors) ----------------
__global__ void canon_kernel(const void* __restrict__ src, float* __restrict__ dst, int n) {
    bool isb = probe_is_bf16(src);
    int i = blockIdx.x * 256 + threadIdx.x;
    if (i < n) dst[i] = read_any(src, i, isb);
}

// ---------------- Canonicalize weights: bf16, TRANSPOSED to [N][K] ----------------
__global__ void canon_bt_kernel(const void* __restrict__ src, ushort_t* __restrict__ dstT,
                                int K, int N) {
    bool isb = probe_is_bf16(src);
    int i = blockIdx.x * 256 + threadIdx.x;
    if (i < K * N) {
        int k = i / N, n = i % N;
        dstT[(size_t)n * K + k] = f2u(read_any(src, i, isb));
    }
}

// ---------------- LN1: raw x (probed) -> bf16 ----------------
__global__ void ln1_kernel(const void* __restrict__ xraw, const float* __restrict__ g,
                           const float* __restrict__ bta, bf16* __restrict__ out) {
    bool xb = probe_is_bf16(xraw);
    int wave = threadIdx.x >> 6, lane = threadIdx.x & 63;
    int t = blockIdx.x * 4 + wave;
    size_t base = (size_t)t * CDIM;
    float v[3];
    #pragma unroll
    for (int i = 0; i < 3; i++) v[i] = read_any(xraw, base + lane + 64 * i, xb);
    float s  = v[0] + v[1] + v[2];
    float s2 = v[0]*v[0] + v[1]*v[1] + v[2]*v[2];
    s = wave_sum(s); s2 = wave_sum(s2);
    float mu = s * (1.0f / CDIM);
    float var = s2 * (1.0f / CDIM) - mu * mu;
    float rs = rsqrtf(var + 1e-5f);
    #pragma unroll
    for (int i = 0; i < 3; i++) {
        int c = lane + 64 * i;
        out[base + c] = f2b((v[i] - mu) * rs * g[c] + bta[c]);
    }
}

// ---------------- LN2: bf16 -> bf16 ----------------
__global__ void ln2_kernel(const bf16* __restrict__ x, const float* __restrict__ g,
                           const float* __restrict__ bta, bf16* __restrict__ out) {
    int wave = threadIdx.x >> 6, lane = threadIdx.x & 63;
    int t = blockIdx.x * 4 + wave;
    size_t base = (size_t)t * CDIM;
    float v[3];
    #pragma unroll
    for (int i = 0; i < 3; i++) v[i] = toF(x[base + lane + 64 * i]);
    float s  = v[0] + v[1] + v[2];
    float s2 = v[0]*v[0] + v[1]*v[1] + v[2]*v[2];
    s = wave_sum(s); s2 = wave_sum(s2);
    float mu = s * (1.0f / CDIM);
    float var = s2 * (1.0f / CDIM) - mu * mu;
    float rs = rsqrtf(var + 1e-5f);
    #pragma unroll
    for (int i = 0; i < 3; i++) {
        int c = lane + 64 * i;
        out[base + c] = f2b((v[i] - mu) * rs * g[c] + bta[c]);
    }
}

// ================= MFMA GEMM: C[M,N] = A[M,K] x BT[N,K]^T (+ epilogue) =================
// Block: 256 thr = 4 waves. Tile M_BLK=128, N_BLK=64, BK=64. LDS rows padded
// +8 bf16 (stride 72) -> row base advances 4 banks/row: 2-way conflicts only.
// mfma_f32_16x16x32_bf16 verified layouts: A/B frag [lane&15][quad*8+j],
// C/D frag row=quad*4+reg, col=lane&15.
// EPI: 0 = plain bf16 store (qkv)
//      1 = +bias +probed-x residual -> bf16 (proj/x1)
//      2 = +bias, exact GELU -> bf16 (mlp1)
//      3 = +bias +bf16-x1 residual -> fp32 out (mlp2)
template <int EPI>
__global__ __launch_bounds__(256) void gemm_kernel(
    const ushort_t* __restrict__ A, const ushort_t* __restrict__ BT,
    const int K, const int N,
    const float* __restrict__ bias,
    const void* __restrict__ res,
    void* __restrict__ out)
{
    __shared__ ushort_t As[128 * 72];
    __shared__ ushort_t Bs[64 * 72];
    int tid = threadIdx.x;
    int t0 = blockIdx.x * 128;
    int n0 = blockIdx.y * 64;
    int lane = tid & 63, wv = tid >> 6;
    int l15 = lane & 15, quad = lane >> 4;

    f32x4 acc[2][4];
    #pragma unroll
    for (int i = 0; i < 2; i++)
        #pragma unroll
        for (int j = 0; j < 4; j++)
            acc[i][j] = (f32x4){0.f, 0.f, 0.f, 0.f};

    for (int kb = 0; kb < K; kb += 64) {
        #pragma unroll
        for (int it = 0; it < 4; it++) {         // A: 128 rows x 8 chunks
            int c = tid + it * 256;
            int m = c >> 3, kc = c & 7;
            *(uint4*)(&As[m * 72 + kc * 8]) =
                *(const uint4*)(&A[(size_t)(t0 + m) * K + kb + kc * 8]);
        }
        #pragma unroll
        for (int it = 0; it < 2; it++) {         // B: 64 rows x 8 chunks
            int c = tid + it * 256;
            int n = c >> 3, kc = c & 7;
            *(uint4*)(&Bs[n * 72 + kc * 8]) =
                *(const uint4*)(&BT[(size_t)(n0 + n) * K + kb + kc * 8]);
        }
        __syncthreads();
        #pragma unroll
        for (int kk = 0; kk < 64; kk += 32) {
            bf16x8 af[2], bfr[4];
            #pragma unroll
            for (int i = 0; i < 2; i++)
                af[i] = *(const bf16x8*)(&As[(wv * 32 + i * 16 + l15) * 72 + kk + quad * 8]);
            #pragma unroll
            for (int j = 0; j < 4; j++)
                bfr[j] = *(const bf16x8*)(&Bs[(j * 16 + l15) * 72 + kk + quad * 8]);
            #pragma unroll
            for (int i = 0; i < 2; i++)
                #pragma unroll
                for (int j = 0; j < 4; j++)
                    acc[i][j] = __builtin_amdgcn_mfma_f32_16x16x32_bf16(af[i], bfr[j], acc[i][j], 0, 0, 0);
        }
        __syncthreads();
    }

    bool xb = false;
    if (EPI == 1) xb = probe_is_bf16(res);

    #pragma unroll
    for (int i = 0; i < 2; i++) {
        #pragma unroll
        for (int j = 0; j < 4; j++) {
            #pragma unroll
            for (int r = 0; r < 4; r++) {
                int row = wv * 32 + i * 16 + quad * 4 + r;
                int col = n0 + j * 16 + l15;
                size_t t = (size_t)(t0 + row);
                float v = acc[i][j][r];
                if (EPI == 0) {
                    ((bf16*)out)[t * N + col] = f2b(v);
                } else if (EPI == 1) {
                    size_t o = t * CDIM + col;
                    ((bf16*)out)[o] = f2b(v + bias[col] + read_any(res, o, xb));
                } else if (EPI == 2) {
                    float a = v + bias[col];
                    ((bf16*)out)[t * N + col] =
                        f2b(0.5f * a * (1.0f + erff(a * 0.70710678118654752f)));
                } else {
                    size_t o = t * CDIM + col;
                    ((float*)out)[o] = v + bias[col] + toF(((const bf16*)res)[o]);
                }
            }
        }
    }
}

// ---------------- Window attention: gather/scatter token-major ----------------
__global__ void attn_kernel(const bf16* __restrict__ qkv, const float* __restrict__ pos_emb,
                            bf16* __restrict__ y) {
    __shared__ int   toks[WS2];
    __shared__ float qs[WS2 * 33];
    __shared__ float ks[WS2 * 33];
    __shared__ float vs[WS2 * 33];
    __shared__ float sc[WS2 * 50];
    int bx = blockIdx.x;
    int h = bx % HEADS;
    int rest = bx / HEADS;
    int win = rest % NWIN;
    int b   = rest / NWIN;
    int wi = win / NWW, wj = win % NWW;
    int tid = threadIdx.x;

    if (tid < WS2) {
        int pi = tid / WS, pj = tid % WS;
        int ui = (wi * WS + pi + 3) % HH;
        int uj = (wj * WS + pj + 3) % WW;
        toks[tid] = (b * HH + ui) * WW + uj;
    }
    __syncthreads();

    for (int idx = tid; idx < WS2 * HD; idx += 64) {
        int p = idx >> 5, d = idx & 31;
        size_t base = (size_t)toks[p] * QKVW + h * HD + d;
        qs[p * 33 + d] = toF(qkv[base]);
        ks[p * 33 + d] = toF(qkv[base + CDIM]);
        vs[p * 33 + d] = toF(qkv[base + 2 * CDIM]);
    }
    __syncthreads();

    bool m_ul = (wi == NWH - 1);
    bool m_lr = (wj == NWW - 1);
    for (int e = tid; e < WS2 * WS2; e += 64) {
        int i = e / WS2, j = e % WS2;
        float acc = 0.f;
        #pragma unroll
        for (int d = 0; d < HD; d++) acc += qs[i * 33 + d] * ks[j * 33 + d];
        acc *= 0.17677669529663689f;
        int pi = i / WS, pj = i % WS, kpi = j / WS, kpj = j % WS;
        acc += pos_emb[(pi - kpi + 6) * 13 + (pj - kpj + 6)];
        if (m_ul && ((pi >= 4) != (kpi >= 4))) acc += NEGV;
        if (m_lr && ((pj >= 4) != (kpj >= 4))) acc += NEGV;
        sc[i * 50 + j] = acc;
    }
    __syncthreads();

    if (tid < WS2) {
        float mx = -INFINITY;
        for (int j = 0; j < WS2; j++) mx = fmaxf(mx, sc[tid * 50 + j]);
        float sum = 0.f;
        for (int j = 0; j < WS2; j++) {
            float ev = expf(sc[tid * 50 + j] - mx);
            sc[tid * 50 + j] = ev;
            sum += ev;
        }
        float inv = 1.0f / sum;
        for (int j = 0; j < WS2; j++) sc[tid * 50 + j] *= inv;
    }
    __syncthreads();

    for (int o = tid; o < WS2 * HD; o += 64) {
        int i = o >> 5, d = o & 31;
        float acc = 0.f;
        for (int j = 0; j < WS2; j++) acc += sc[i * 50 + j] * vs[j * 33 + d];
        y[(size_t)toks[i] * CDIM + h * HD + d] = f2b(acc);
    }
}

extern "C" void kernel_launch(void* const* d_in, const int* in_sizes, int n_in,
                              void* d_out, int out_size, void* d_ws, size_t ws_size,
                              hipStream_t stream) {
    float* out = (float*)d_out;   // reference output dtype: float32

    // Workspace:
    //   bufA bf16 [NTOK,192]  ln1 / ln2 out        38,535,168 B
    //   bufQ bf16 [NTOK,576]  qkv                 115,605,504 B
    //   bufY bf16 [NTOK,192]  attn out            38,535,168 B
    //   bufX bf16 [NTOK,192]  x1                   38,535,168 B
    //   cW   fp32 small params (~3K floats)            12,288 B
    //   cT   bf16 transposed weights (442,368 el)    884,736 B
    // hid [NTOK,768] overlays bufQ+bufY (dead by mlp1). Total ~232.1 MB.
    size_t szA = (size_t)NTOK * CDIM * sizeof(bf16);
    size_t szQ = (size_t)NTOK * QKVW * sizeof(bf16);
    size_t szY = (size_t)NTOK * CDIM * sizeof(bf16);
    size_t szX = (size_t)NTOK * CDIM * sizeof(bf16);
    size_t szP = 3072 * sizeof(float);
    size_t szT = 442368 * sizeof(ushort_t);
    if (ws_size < szA + szQ + szY + szX + szP + szT) return;
    bf16*     bufA = (bf16*)d_ws;
    bf16*     bufQ = (bf16*)((char*)d_ws + szA);
    bf16*     bufY = (bf16*)((char*)d_ws + szA + szQ);
    bf16*     bufX = (bf16*)((char*)d_ws + szA + szQ + szY);
    float*    cW   = (float*)((char*)d_ws + szA + szQ + szY + szX);
    ushort_t* cT   = (ushort_t*)((char*)d_ws + szA + szQ + szY + szX + szP);
    bf16*     hid  = bufQ;   // [NTOK,768] overlay

    float* cBout = cW + 0;      // 192
    float* cPe   = cW + 192;    // 169
    float* cL1g  = cW + 384;
    float* cL1b  = cW + 576;
    float* cL2g  = cW + 768;
    float* cL2b  = cW + 960;
    float* cB1   = cW + 1152;   // 768
    float* cB2   = cW + 1920;   // 192

    ushort_t* tWqkv = cT + 0;        // [576][192]
    ushort_t* tWout = cT + 110592;   // [192][192]
    ushort_t* tW1   = cT + 147456;   // [768][192]
    ushort_t* tW2   = cT + 294912;   // [192][768]

    dim3 b256(256), b64(64);
    #define CANON(src, dst, n) canon_kernel<<<((n)+255)/256, b256, 0, stream>>>((src), (dst), (n))
    CANON(d_in[3],  cBout, 192);
    CANON(d_in[4],  cPe,   169);
    CANON(d_in[5],  cL1g,  192);
    CANON(d_in[6],  cL1b,  192);
    CANON(d_in[7],  cL2g,  192);
    CANON(d_in[8],  cL2b,  192);
    CANON(d_in[10], cB1,   768);
    CANON(d_in[12], cB2,   192);
    #undef CANON
    #define CANONT(src, dst, K, N) \
        canon_bt_kernel<<<((K)*(N)+255)/256, b256, 0, stream>>>((src), (dst), (K), (N))
    CANONT(d_in[1],  tWqkv, CDIM, QKVW);
    CANONT(d_in[2],  tWout, CDIM, CDIM);
    CANONT(d_in[9],  tW1,   CDIM, MLPW);
    CANONT(d_in[11], tW2,   MLPW, CDIM);
    #undef CANONT

    int gLN = NTOK / 4;             // 25088
    int gM  = NTOK / 128;           // 784
    int gAT = BATCH * NWIN * HEADS; // 12288

    ln1_kernel<<<gLN, b256, 0, stream>>>(d_in[0], cL1g, cL1b, bufA);
    gemm_kernel<0><<<dim3(gM, QKVW / 64), b256, 0, stream>>>(
        (const ushort_t*)bufA, tWqkv, CDIM, QKVW, nullptr, nullptr, bufQ);
    attn_kernel<<<gAT, b64, 0, stream>>>(bufQ, cPe, bufY);
    gemm_kernel<1><<<dim3(gM, CDIM / 64), b256, 0, stream>>>(
        (const ushort_t*)bufY, tWout, CDIM, CDIM, cBout, d_in[0], bufX);
    ln2_kernel<<<gLN, b256, 0, stream>>>(bufX, cL2g, cL2b, bufA);
    gemm_kernel<2><<<dim3(gM, MLPW / 64), b256, 0, stream>>>(
        (const ushort_t*)bufA, tW1, CDIM, MLPW, cB1, nullptr, hid);
    gemm_kernel<3><<<dim3(gM, CDIM / 64), b256, 0, stream>>>(
        (const ushort_t*)hid, tW2, MLPW, CDIM, cB2, bufX, out);
}